// Round 1
// baseline (446.311 us; speedup 1.0000x reference)
//
#include <hip/hip_runtime.h>
#include <math.h>

// Problem: B=8, C=64, H=W=256. Conv-sigma: OC=32, VALID 3x3 -> 254x254.
// Blur: stride 2, reflect pad 1 -> out [64][8][128][128] fp32.
//
// ws layout (floats):
//   [0, 256)           acc[b][oc]      (8*32) conv+relu spatial sums
//   [256, 328)         kern[b][9]      gaussian kernels
//   [328, 328+18432)   wt[ic][tap][oc] transposed conv weights (64*9*32)

#define WS_ACC  0
#define WS_KERN 256
#define WS_WT   328

// ---------------- prep: zero accumulators + transpose weights ----------------
__global__ void prep_kernel(const float* __restrict__ w, float* __restrict__ ws) {
    int i = blockIdx.x * blockDim.x + threadIdx.x;
    if (i < 256) ws[WS_ACC + i] = 0.f;
    if (i < 64 * 9 * 32) {
        int oc  = i & 31;
        int t   = i >> 5;       // ic*9 + tap
        int tap = t % 9;
        int ic  = t / 9;
        // original layout: w[oc][ic][ky][kx] = w[oc*576 + ic*9 + tap]
        ws[WS_WT + i] = w[oc * 576 + ic * 9 + tap];
    }
}

// ---------------- conv 3x3 VALID + relu + spatial-sum reduce ----------------
// grid: (16, 16, 8)  tiles of 16x16 output pixels, block 256 threads.
__global__ __launch_bounds__(256, 4) void conv_reduce_kernel(
        const float* __restrict__ x, const float* __restrict__ wt,
        float* __restrict__ acc_out) {
    __shared__ float sx[16 * 18 * 18];   // 16 ic x 18 x 18 input tile (20.7 KB)
    __shared__ float sred[128];

    const int b   = blockIdx.z;
    const int ox0 = blockIdx.x * 16;
    const int oy0 = blockIdx.y * 16;
    const int tid = threadIdx.x;
    const int px  = tid & 15;
    const int py  = tid >> 4;
    const int ox  = ox0 + px;
    const int oy  = oy0 + py;
    const bool valid = (ox < 254) && (oy < 254);

    float acc[32];
#pragma unroll
    for (int i = 0; i < 32; ++i) acc[i] = 0.f;

    const float* xb = x + (size_t)b * 64 * 256 * 256;

    for (int icc = 0; icc < 4; ++icc) {
        __syncthreads();
        // stage 16 ic x 18 x 18
        for (int idx = tid; idx < 16 * 18 * 18; idx += 256) {
            int ic = idx / 324;
            int r  = idx - ic * 324;
            int ly = r / 18;
            int lx = r - ly * 18;
            int gy = oy0 + ly;
            int gx = ox0 + lx;
            float v = 0.f;
            if (gy < 256 && gx < 256)
                v = xb[(size_t)(icc * 16 + ic) * 65536 + gy * 256 + gx];
            sx[idx] = v;
        }
        __syncthreads();

#pragma unroll 1
        for (int ic = 0; ic < 16; ++ic) {
            const float* srow  = sx + ic * 324 + py * 18 + px;
            const float* wbase = wt + (size_t)((icc * 16 + ic) * 9) * 32;
#pragma unroll
            for (int dy = 0; dy < 3; ++dy) {
#pragma unroll
                for (int dx = 0; dx < 3; ++dx) {
                    const float xv = srow[dy * 18 + dx];
                    const float* wrow = wbase + (dy * 3 + dx) * 32;  // uniform -> s_load
#pragma unroll
                    for (int oc = 0; oc < 32; ++oc)
                        acc[oc] = fmaf(wrow[oc], xv, acc[oc]);
                }
            }
        }
    }

    // relu (invalid pixels contribute 0) + block reduction per oc
    const int lane = tid & 63;
    const int wv   = tid >> 6;
#pragma unroll
    for (int oc = 0; oc < 32; ++oc) {
        float v = valid ? fmaxf(acc[oc], 0.f) : 0.f;
#pragma unroll
        for (int off = 32; off > 0; off >>= 1)
            v += __shfl_down(v, off, 64);
        if (lane == 0) sred[wv * 32 + oc] = v;
    }
    __syncthreads();
    if (tid < 32) {
        float v = sred[tid] + sred[32 + tid] + sred[64 + tid] + sred[96 + tid];
        atomicAdd(&acc_out[b * 32 + tid], v);
    }
}

// ---------------- sigma -> gaussian kernels ----------------
__global__ void sigma_kernel(const float* __restrict__ acc,
                             const float* __restrict__ wfc,
                             const float* __restrict__ bfc,
                             float* __restrict__ kern) {
    int b = threadIdx.x;
    if (b >= 8) return;
    float z = 0.f;
    for (int i = 0; i < 32; ++i) z += acc[b * 32 + i] * wfc[i];
    z = z * (1.0f / (254.0f * 254.0f)) + bfc[0];
    float sig = 1.0f / (1.0f + expf(-z));
    float s   = fmaxf(sig, 1e-4f);
    // normalized gaussian: prefactor cancels; only exp(-0.5*d^2/s^2) matters
    float inv2 = 0.5f / (s * s);
    float e1 = expf(-inv2);        // d^2 = 1 (edges)
    float e2 = expf(-2.0f * inv2); // d^2 = 2 (corners)
    float norm = 1.0f + 4.0f * e1 + 4.0f * e2;
    float inv_norm = 1.0f / norm;
    for (int dy = 0; dy < 3; ++dy)
        for (int dx = 0; dx < 3; ++dx) {
            int d2 = (dy - 1) * (dy - 1) + (dx - 1) * (dx - 1);
            float v = (d2 == 0) ? 1.0f : ((d2 == 1) ? e1 : e2);
            kern[b * 9 + dy * 3 + dx] = v * inv_norm;
        }
}

// ---------------- per-sample stride-2 blur, reflect pad 1 ----------------
// grid: (64 row-pairs, 8 b, 64 c), block 256 = 128 ox x 2 oy
__global__ __launch_bounds__(256) void blur_kernel(
        const float* __restrict__ x, const float* __restrict__ kern,
        float* __restrict__ out) {
    const int c   = blockIdx.z;
    const int b   = blockIdx.y;
    const int tid = threadIdx.x;
    const int ox  = tid & 127;
    const int oy  = blockIdx.x * 2 + (tid >> 7);

    const float* k = kern + b * 9;   // uniform -> scalar loads
    const float* xb = x + ((size_t)(b * 64 + c)) * 65536;

    float accv = 0.f;
#pragma unroll
    for (int dy = 0; dy < 3; ++dy) {
        int iy = 2 * oy + dy - 1;
        if (iy < 0) iy = 1;           // reflect (no edge repeat); iy<=255 always
        const float* row = xb + iy * 256;
#pragma unroll
        for (int dx = 0; dx < 3; ++dx) {
            int ix = 2 * ox + dx - 1;
            if (ix < 0) ix = 1;
            accv = fmaf(k[dy * 3 + dx], row[ix], accv);
        }
    }
    out[(((size_t)c * 8 + b) * 128 + oy) * 128 + ox] = accv;
}

extern "C" void kernel_launch(void* const* d_in, const int* in_sizes, int n_in,
                              void* d_out, int out_size, void* d_ws, size_t ws_size,
                              hipStream_t stream) {
    const float* x       = (const float*)d_in[0];
    const float* w_sigma = (const float*)d_in[1];
    const float* w_fc    = (const float*)d_in[2];
    const float* b_fc    = (const float*)d_in[3];
    float* out = (float*)d_out;
    float* ws  = (float*)d_ws;

    prep_kernel<<<72, 256, 0, stream>>>(w_sigma, ws);
    conv_reduce_kernel<<<dim3(16, 16, 8), 256, 0, stream>>>(
        x, ws + WS_WT, ws + WS_ACC);
    sigma_kernel<<<1, 64, 0, stream>>>(ws + WS_ACC, w_fc, b_fc, ws + WS_KERN);
    blur_kernel<<<dim3(64, 8, 64), 256, 0, stream>>>(x, ws + WS_KERN, out);
}

// Round 5
// 438.045 us; speedup vs baseline: 1.0189x; 1.0189x over previous
//
#include <hip/hip_runtime.h>
#include <math.h>

// Problem: B=8, C=64, H=W=256. Conv-sigma: OC=32, VALID 3x3 -> 254x254.
// Blur: stride 2, reflect pad 1 -> out [64][8][128][128] fp32.
//
// ws layout (floats):
//   [0, 256)           acc[b][oc]      (8*32) conv+relu spatial sums
//   [256, 328)         kern[b][9]      gaussian kernels
//   [328, 328+18432)   wt[ic][tap][oc] transposed conv weights (64*9*32)

#define WS_ACC  0
#define WS_KERN 256
#define WS_WT   328

// ---------------- prep: zero accumulators + transpose weights ----------------
__global__ void prep_kernel(const float* __restrict__ w, float* __restrict__ ws) {
    int i = blockIdx.x * blockDim.x + threadIdx.x;
    if (i < 256) ws[WS_ACC + i] = 0.f;
    if (i < 64 * 9 * 32) {
        int oc  = i & 31;
        int t   = i >> 5;       // ic*9 + tap
        int tap = t % 9;
        int ic  = t / 9;
        ws[WS_WT + i] = w[oc * 576 + ic * 9 + tap];
    }
}

// ---------------- conv 3x3 VALID + relu + spatial-sum reduce ----------------
// grid: (16, 16, 8)  tiles of 16x16 output pixels, block 256 threads.
// (identical to the Round-1 version that measured 285 us / VALUBusy 60%)
__global__ __launch_bounds__(256, 4) void conv_reduce_kernel(
        const float* __restrict__ x, const float* __restrict__ wt,
        float* __restrict__ acc_out) {
    __shared__ float sx[16 * 18 * 18];   // 16 ic x 18 x 18 input tile (20.7 KB)
    __shared__ float sred[128];

    const int b   = blockIdx.z;
    const int ox0 = blockIdx.x * 16;
    const int oy0 = blockIdx.y * 16;
    const int tid = threadIdx.x;
    const int px  = tid & 15;
    const int py  = tid >> 4;
    const int ox  = ox0 + px;
    const int oy  = oy0 + py;
    const bool valid = (ox < 254) && (oy < 254);

    float acc[32];
#pragma unroll
    for (int i = 0; i < 32; ++i) acc[i] = 0.f;

    const float* xb = x + (size_t)b * 64 * 256 * 256;

    for (int icc = 0; icc < 4; ++icc) {
        __syncthreads();
        for (int idx = tid; idx < 16 * 18 * 18; idx += 256) {
            int ic = idx / 324;
            int r  = idx - ic * 324;
            int ly = r / 18;
            int lx = r - ly * 18;
            int gy = oy0 + ly;
            int gx = ox0 + lx;
            float v = 0.f;
            if (gy < 256 && gx < 256)
                v = xb[(size_t)(icc * 16 + ic) * 65536 + gy * 256 + gx];
            sx[idx] = v;
        }
        __syncthreads();

#pragma unroll 1
        for (int ic = 0; ic < 16; ++ic) {
            const float* srow  = sx + ic * 324 + py * 18 + px;
            const float* wbase = wt + (size_t)((icc * 16 + ic) * 9) * 32;
#pragma unroll
            for (int dy = 0; dy < 3; ++dy) {
#pragma unroll
                for (int dx = 0; dx < 3; ++dx) {
                    const float xv = srow[dy * 18 + dx];
                    const float* wrow = wbase + (dy * 3 + dx) * 32;  // uniform -> s_load
#pragma unroll
                    for (int oc = 0; oc < 32; ++oc)
                        acc[oc] = fmaf(wrow[oc], xv, acc[oc]);
                }
            }
        }
    }

    const int lane = tid & 63;
    const int wv   = tid >> 6;
#pragma unroll
    for (int oc = 0; oc < 32; ++oc) {
        float v = valid ? fmaxf(acc[oc], 0.f) : 0.f;
#pragma unroll
        for (int off = 32; off > 0; off >>= 1)
            v += __shfl_down(v, off, 64);
        if (lane == 0) sred[wv * 32 + oc] = v;
    }
    __syncthreads();
    if (tid < 32) {
        float v = sred[tid] + sred[32 + tid] + sred[64 + tid] + sred[96 + tid];
        atomicAdd(&acc_out[b * 32 + tid], v);
    }
}

// ---------------- sigma -> gaussian kernels ----------------
__global__ void sigma_kernel(const float* __restrict__ acc,
                             const float* __restrict__ wfc,
                             const float* __restrict__ bfc,
                             float* __restrict__ kern) {
    int b = threadIdx.x;
    if (b >= 8) return;
    float z = 0.f;
    for (int i = 0; i < 32; ++i) z += acc[b * 32 + i] * wfc[i];
    z = z * (1.0f / (254.0f * 254.0f)) + bfc[0];
    float sig = 1.0f / (1.0f + expf(-z));
    float s   = fmaxf(sig, 1e-4f);
    float inv2 = 0.5f / (s * s);
    float e1 = expf(-inv2);
    float e2 = expf(-2.0f * inv2);
    float inv_norm = 1.0f / (1.0f + 4.0f * e1 + 4.0f * e2);
    for (int dy = 0; dy < 3; ++dy)
        for (int dx = 0; dx < 3; ++dx) {
            int d2 = (dy - 1) * (dy - 1) + (dx - 1) * (dx - 1);
            float v = (d2 == 0) ? 1.0f : ((d2 == 1) ? e1 : e2);
            kern[b * 9 + dy * 3 + dx] = v * inv_norm;
        }
}

// ---------------- per-sample stride-2 blur, reflect pad 1 ----------------
// grid (16 oy-blocks, 8 b, 64 c), block 256 = 32 x-threads x 8 oy.
// Each thread: 4 outputs via 2 float4 + 1 scalar per input row.
__global__ __launch_bounds__(256) void blur_kernel(
        const float* __restrict__ x, const float* __restrict__ kern,
        float* __restrict__ out) {
    const int c = blockIdx.z, b = blockIdx.y;
    const int tid = threadIdx.x;
    const int qx = tid & 31;                 // 4-output group
    const int oy = blockIdx.x * 8 + (tid >> 5);

    const float* k = kern + b * 9;
    float k0 = k[0], k1 = k[1], k2 = k[2], k3 = k[3], k4 = k[4];
    float k5 = k[5], k6 = k[6], k7 = k[7], k8 = k[8];
    const float* xb = x + ((size_t)(b * 64 + c)) * 65536;

    float o0 = 0.f, o1 = 0.f, o2 = 0.f, o3 = 0.f;
#pragma unroll
    for (int dy = 0; dy < 3; ++dy) {
        int iy = 2 * oy + dy - 1;
        if (iy < 0) iy = 1;                   // reflect
        const float* row = xb + iy * 256;
        const float4 f0 = *(const float4*)(row + 8 * qx);
        const float4 f1 = *(const float4*)(row + 8 * qx + 4);
        const float sm1 = (qx == 0) ? row[1] : row[8 * qx - 1];
        const float ka = (dy == 0) ? k0 : (dy == 1) ? k3 : k6;
        const float kb = (dy == 0) ? k1 : (dy == 1) ? k4 : k7;
        const float kc = (dy == 0) ? k2 : (dy == 1) ? k5 : k8;
        o0 = fmaf(ka, sm1,  fmaf(kb, f0.x, fmaf(kc, f0.y, o0)));
        o1 = fmaf(ka, f0.y, fmaf(kb, f0.z, fmaf(kc, f0.w, o1)));
        o2 = fmaf(ka, f0.w, fmaf(kb, f1.x, fmaf(kc, f1.y, o2)));
        o3 = fmaf(ka, f1.y, fmaf(kb, f1.z, fmaf(kc, f1.w, o3)));
    }
    float4 ov = make_float4(o0, o1, o2, o3);
    *(float4*)(out + (((size_t)c * 8 + b) * 128 + oy) * 128 + 4 * qx) = ov;
}

extern "C" void kernel_launch(void* const* d_in, const int* in_sizes, int n_in,
                              void* d_out, int out_size, void* d_ws, size_t ws_size,
                              hipStream_t stream) {
    const float* x       = (const float*)d_in[0];
    const float* w_sigma = (const float*)d_in[1];
    const float* w_fc    = (const float*)d_in[2];
    const float* b_fc    = (const float*)d_in[3];
    float* out = (float*)d_out;
    float* ws  = (float*)d_ws;

    prep_kernel<<<72, 256, 0, stream>>>(w_sigma, ws);
    conv_reduce_kernel<<<dim3(16, 16, 8), 256, 0, stream>>>(
        x, ws + WS_WT, ws + WS_ACC);
    sigma_kernel<<<1, 64, 0, stream>>>(ws + WS_ACC, w_fc, b_fc, ws + WS_KERN);
    blur_kernel<<<dim3(16, 8, 64), 256, 0, stream>>>(x, ws + WS_KERN, out);
}

// Round 6
// 304.154 us; speedup vs baseline: 1.4674x; 1.4402x over previous
//
#include <hip/hip_runtime.h>
#include <math.h>

// B=8, C=64, H=W=256. conv_sigma: OC=32, VALID 3x3 -> 254x254 (bf16 MFMA).
// blur: stride 2, reflect pad 1, sigma/kern computed inline -> out [64][8][128][128].
//
// ws layout (float index): acc[0,256) ; wtb bf16 @ float-ofs 512
//   wtb[tap][oc][ic] (9*32*64 ushorts = 36 KB), ic-contiguous for B-frags.

typedef __attribute__((ext_vector_type(8))) short s8v;   // 8 bf16
typedef __attribute__((ext_vector_type(4))) float f4v;   // 4 f32

static __device__ inline unsigned short f2bf(float f) {
    union { float f; unsigned int u; } v; v.f = f;
    unsigned int u = v.u;
    unsigned int r = u + 0x7FFFu + ((u >> 16) & 1u);
    return (unsigned short)(r >> 16);
}

// ---------------- prep: zero acc + weights -> bf16 [tap][oc][ic] ----------------
__global__ void prep_kernel(const float* __restrict__ w, float* __restrict__ ws) {
    int i = blockIdx.x * blockDim.x + threadIdx.x;
    if (i < 256) ws[i] = 0.f;
    if (i < 9 * 32 * 64) {
        int ic  = i & 63;
        int oc  = (i >> 6) & 31;
        int tap = i >> 11;
        unsigned short* wtb = (unsigned short*)(ws + 512);
        wtb[i] = f2bf(w[oc * 576 + ic * 9 + tap]);
    }
}

// ---------------- conv 3x3 VALID (bf16 MFMA) + relu + spatial reduce ----------------
// grid (8 bx, 32 by, 8 b), block 256 = 4 waves. Block: 8 oy x 32 ox x 32 oc.
// LDS slab: 10 rows x 34 px x 64 ic bf16, [pixel][ic], XOR-swizzled 16B blocks.
__global__ __launch_bounds__(256) void conv_mfma_kernel(
        const float* __restrict__ x, const unsigned short* __restrict__ wtb,
        float* __restrict__ acc_out) {
    __shared__ __align__(16) unsigned char sx[340 * 128];  // 43520 B
    __shared__ float sred[4][32];

    const int bx = blockIdx.x, by = blockIdx.y, b = blockIdx.z;
    const int ox0 = bx * 32, oy0 = by * 8;
    const int tid = threadIdx.x;
    const int lane = tid & 63, w = tid >> 6;
    const int m = lane & 15, q = lane >> 4;

    // ---- stage: 340 pixels x 64 ic, fp32->bf16, packed b32 writes ----
    const float* xb = x + (size_t)b * 64 * 65536;
    for (int i = tid; i < 340 * 32; i += 256) {
        int p = i % 340;          // pixel (fast -> coalesced global reads)
        int r = i / 340;          // ic pair 0..31
        int yy = p / 34, xx = p - yy * 34;
        int y = oy0 + yy, xc = ox0 + xx;
        float v0 = 0.f, v1 = 0.f;
        if (y < 256 && xc < 256) {
            const float* src = xb + (size_t)(2 * r) * 65536 + y * 256 + xc;
            v0 = src[0];
            v1 = src[65536];
        }
        unsigned int pk = (unsigned int)f2bf(v0) | ((unsigned int)f2bf(v1) << 16);
        int quad = (r >> 2) ^ (p & 7);
        *(unsigned int*)(sx + p * 128 + quad * 16 + (r & 3) * 4) = pk;
    }
    __syncthreads();

    // ---- K-loop: runtime 3x3 tap loop, 16 MFMA per tap ----
    f4v acc[4][2];
#pragma unroll
    for (int mt = 0; mt < 4; ++mt)
#pragma unroll
        for (int nt = 0; nt < 2; ++nt) acc[mt][nt] = (f4v)0.f;

    int pbase[4];
#pragma unroll
    for (int mt = 0; mt < 4; ++mt)
        pbase[mt] = (2 * w + (mt >> 1)) * 34 + (mt & 1) * 16 + m;

#pragma unroll 1
    for (int dy = 0; dy < 3; ++dy) {
#pragma unroll 1
        for (int dx = 0; dx < 3; ++dx) {
            const unsigned short* wt_tap = wtb + (dy * 3 + dx) * 2048;
#pragma unroll
            for (int kc = 0; kc < 2; ++kc) {
                s8v b0 = *(const s8v*)(wt_tap + m * 64 + kc * 32 + q * 8);
                s8v b1 = *(const s8v*)(wt_tap + (16 + m) * 64 + kc * 32 + q * 8);
#pragma unroll
                for (int mt = 0; mt < 4; ++mt) {
                    int p = pbase[mt] + dy * 34 + dx;
                    int quad = (kc * 4 + q) ^ (p & 7);
                    s8v afr = *(const s8v*)(sx + p * 128 + quad * 16);
                    acc[mt][0] = __builtin_amdgcn_mfma_f32_16x16x32_bf16(afr, b0, acc[mt][0], 0, 0, 0);
                    acc[mt][1] = __builtin_amdgcn_mfma_f32_16x16x32_bf16(afr, b1, acc[mt][1], 0, 0, 0);
                }
            }
        }
    }

    // ---- epilogue: relu + mask invalid pixels + reduce ----
    // D layout: col(oc) = lane&15, row(pixel-x) = (lane>>4)*4 + reg
    float s0 = 0.f, s1 = 0.f;
#pragma unroll
    for (int mt = 0; mt < 4; ++mt) {
        int oy = oy0 + 2 * w + (mt >> 1);
        int oxb = ox0 + (mt & 1) * 16 + q * 4;
#pragma unroll
        for (int reg = 0; reg < 4; ++reg) {
            bool val = (oxb + reg < 254) && (oy < 254);
            if (val) {
                s0 += fmaxf(acc[mt][0][reg], 0.f);
                s1 += fmaxf(acc[mt][1][reg], 0.f);
            }
        }
    }
    s0 += __shfl_xor(s0, 16, 64); s0 += __shfl_xor(s0, 32, 64);
    s1 += __shfl_xor(s1, 16, 64); s1 += __shfl_xor(s1, 32, 64);
    if (lane < 16) { sred[w][lane] = s0; sred[w][16 + lane] = s1; }
    __syncthreads();
    if (tid < 32)
        atomicAdd(&acc_out[b * 32 + tid],
                  sred[0][tid] + sred[1][tid] + sred[2][tid] + sred[3][tid]);
}

// ---------------- blur with inline sigma->kernel ----------------
// grid (16 oy-blocks, 8 b, 64 c), block 256 = 32 x-threads x 8 oy.
// Every thread recomputes the 9 kernel taps (wave-uniform, ~60 flops, L2-hot).
__global__ __launch_bounds__(256) void blur_kernel(
        const float* __restrict__ x, const float* __restrict__ acc,
        const float* __restrict__ wfc, const float* __restrict__ bfc,
        float* __restrict__ out) {
    const int c = blockIdx.z, b = blockIdx.y;
    const int tid = threadIdx.x;
    const int qx = tid & 31;                 // 4-output group
    const int oy = blockIdx.x * 8 + (tid >> 5);

    // sigma branch tail: fc + sigmoid + gaussian taps (uniform per block)
    float z = 0.f;
#pragma unroll
    for (int i = 0; i < 32; ++i) z += acc[b * 32 + i] * wfc[i];
    z = z * (1.0f / (254.0f * 254.0f)) + bfc[0];
    float sig = 1.0f / (1.0f + __expf(-z));
    float s   = fmaxf(sig, 1e-4f);
    float inv2 = 0.5f / (s * s);
    float e1 = __expf(-inv2);
    float e2 = __expf(-2.0f * inv2);
    float inv_norm = 1.0f / (1.0f + 4.0f * e1 + 4.0f * e2);
    const float kC = inv_norm;            // center
    const float kE = e1 * inv_norm;       // edge
    const float kD = e2 * inv_norm;       // diagonal

    const float* xb = x + ((size_t)(b * 64 + c)) * 65536;

    float o0 = 0.f, o1 = 0.f, o2 = 0.f, o3 = 0.f;
#pragma unroll
    for (int dy = 0; dy < 3; ++dy) {
        int iy = 2 * oy + dy - 1;
        if (iy < 0) iy = 1;                   // reflect
        const float* row = xb + iy * 256;
        const float4 f0 = *(const float4*)(row + 8 * qx);
        const float4 f1 = *(const float4*)(row + 8 * qx + 4);
        const float sm1 = (qx == 0) ? row[1] : row[8 * qx - 1];
        const float ka = (dy == 1) ? kE : kD;
        const float kb = (dy == 1) ? kC : kE;
        const float kc = (dy == 1) ? kE : kD;
        o0 = fmaf(ka, sm1,  fmaf(kb, f0.x, fmaf(kc, f0.y, o0)));
        o1 = fmaf(ka, f0.y, fmaf(kb, f0.z, fmaf(kc, f0.w, o1)));
        o2 = fmaf(ka, f0.w, fmaf(kb, f1.x, fmaf(kc, f1.y, o2)));
        o3 = fmaf(ka, f1.y, fmaf(kb, f1.z, fmaf(kc, f1.w, o3)));
    }
    float4 ov = make_float4(o0, o1, o2, o3);
    *(float4*)(out + (((size_t)c * 8 + b) * 128 + oy) * 128 + 4 * qx) = ov;
}

extern "C" void kernel_launch(void* const* d_in, const int* in_sizes, int n_in,
                              void* d_out, int out_size, void* d_ws, size_t ws_size,
                              hipStream_t stream) {
    const float* x       = (const float*)d_in[0];
    const float* w_sigma = (const float*)d_in[1];
    const float* w_fc    = (const float*)d_in[2];
    const float* b_fc    = (const float*)d_in[3];
    float* out = (float*)d_out;
    float* ws  = (float*)d_ws;
    const unsigned short* wtb = (const unsigned short*)(ws + 512);

    prep_kernel<<<72, 256, 0, stream>>>(w_sigma, ws);
    conv_mfma_kernel<<<dim3(8, 32, 8), 256, 0, stream>>>(x, wtb, ws);
    blur_kernel<<<dim3(16, 8, 64), 256, 0, stream>>>(x, ws, w_fc, b_fc, out);
}